// Round 3
// baseline (4161.855 us; speedup 1.0000x reference)
//
#include <hip/hip_runtime.h>
#include <cstddef>

// LSTM_27934467293427 — R3.
// R2 was LDS-pipe bound: 24 ds_read_b128/thread/step (x+h broadcast through
// LDS) ~2000 cy/step, VALU 15% idle. R3:
//  - wave-level half-split m = wave&1: x half is wave-uniform -> loaded via
//    addrspace(4) pointer => s_load_dwordx16 on the SMEM pipe (0 LDS reads).
//  - h read as wave-uniform ds_read_b128 broadcasts (8/wave/step).
//  - no shfl reduce: halves write gA/gB partial arrays; cell wave adds.
//  - weights held in VGPRs via asm volatile global_load (cannot be remat'd).

namespace {

constexpr int B_ = 256;
constexpr int S_ = 2048;
constexpr int E_ = 128;
constexpr int H_ = 64;
constexpr int H2_ = 2;
constexpr int NTHR = 512;
constexpr int KO4_ = 104; // 26 head outputs * 4 lanes

typedef const __attribute__((address_space(4))) float cfloat;

__device__ __forceinline__ float sigm(float x) {
    return __builtin_amdgcn_rcpf(1.0f + __expf(-x));
}
__device__ __forceinline__ float tanh_fast(float x) {
    return 1.0f - 2.0f * __builtin_amdgcn_rcpf(1.0f + __expf(2.0f * x));
}
__device__ __forceinline__ float dot4(float4 a, float4 b) {
    return a.x * b.x + a.y * b.y + a.z * b.z + a.w * b.w;
}

__global__ __launch_bounds__(NTHR, 2)
void lstm_fused(const float* __restrict__ x,       // (B,S,E)
                const int* __restrict__ lengths,   // (B,)
                const float* __restrict__ Wih,     // (256,128)
                const float* __restrict__ Whh,     // (256,64)
                const float* __restrict__ bih,     // (256,)
                const float* __restrict__ bhh,     // (256,)
                const float* __restrict__ hWih,    // (13,2,64)
                const float* __restrict__ hWhh,    // (13,2,2)
                const float* __restrict__ hbih,    // (13,2)
                const float* __restrict__ hbhh,    // (13,2)
                float* __restrict__ out)           // (13,256,2)
{
    const int b = blockIdx.x;
    const int t = threadIdx.x;
    const int w = t >> 6;         // wave id 0..7
    const int l = t & 63;         // lane
    const int sct = w >> 1;       // gate sector: gates 64*sct .. +63
    const int m = w & 1;          // dot half: x[64m:64m+64], h[32m:32m+32]
    const int j = sct * 64 + l;   // gate owned by this thread (for half m)

    int len = lengths[b];
    len = (len < 1) ? 1 : (len > S_ ? S_ : len);

    __shared__ __align__(16) float h_lds[2][H_];
    __shared__ __align__(16) float gA[256];  // m=0 partials (+bias)
    __shared__ __align__(16) float gB[256];  // m=1 partials

    // ---- weights: asm loads => guaranteed VGPR residency, no remat ----
    float4 wx[16];  // Wih[j][64m .. 64m+63]
    float4 wh[8];   // Whh[j][32m .. 32m+31]
    {
        const float4* wr = (const float4*)(Wih + j * E_ + m * 64);
        #pragma unroll
        for (int i = 0; i < 16; ++i)
            asm volatile("global_load_dwordx4 %0, %1, off"
                         : "=v"(wx[i]) : "v"(wr + i));
        const float4* hr = (const float4*)(Whh + j * H_ + m * 32);
        #pragma unroll
        for (int i = 0; i < 8; ++i)
            asm volatile("global_load_dwordx4 %0, %1, off"
                         : "=v"(wh[i]) : "v"(hr + i));
    }
    const float bsum = bih[j] + bhh[j];

    // ---- head weights (threads 0..103), asm-pinned ----
    const int q = t & 3, gb = t >> 2;
    float4 wk[4] = {};
    float whh0 = 0.f, whh1 = 0.f, hbsum = 0.f;
    if (t < KO4_) {
        const float4* kr = (const float4*)(hWih + gb * H_ + q * 16);
        #pragma unroll
        for (int e = 0; e < 4; ++e)
            asm volatile("global_load_dwordx4 %0, %1, off"
                         : "=v"(wk[e]) : "v"(kr + e));
        whh0 = hWhh[gb * 2 + 0];
        whh1 = hWhh[gb * 2 + 1];
        hbsum = hbih[gb] + hbhh[gb];
    }
    asm volatile("s_waitcnt vmcnt(0)" ::: "memory");

    float hk = 0.f;  // head state (lanes q==0, t<104)
    float c = 0.f;   // cell state (wave 7)

    if (t < H_) h_lds[1][t] = 0.f;  // h_{-1} = 0 at parity (0+1)&1
    __syncthreads();

    // wave-uniform x half base, constant addrspace => s_load
    cfloat* xrow = (cfloat*)(x + (size_t)b * S_ * E_ + m * 64);

    for (int u = 0;; ++u) {
        // ---- phase 1: gate partial dots ----
        if (u < len) {
            cfloat* xr = xrow + (size_t)u * E_;
            const float4* hs = (const float4*)(h_lds[(u + 1) & 1] + m * 32);
            float p0 = 0.f, p1 = 0.f, p2 = 0.f, p3 = 0.f;
            #pragma unroll
            for (int i = 0; i < 16; ++i) {
                p0 += wx[i].x * xr[4 * i + 0];
                p1 += wx[i].y * xr[4 * i + 1];
                p2 += wx[i].z * xr[4 * i + 2];
                p3 += wx[i].w * xr[4 * i + 3];
            }
            #pragma unroll
            for (int i = 0; i < 8; i += 2) {
                const float4 hv0 = hs[i], hv1 = hs[i + 1];
                p0 += wh[i].x * hv0.x;     p1 += wh[i].y * hv0.y;
                p2 += wh[i].z * hv0.z;     p3 += wh[i].w * hv0.w;
                p0 += wh[i + 1].x * hv1.x; p1 += wh[i + 1].y * hv1.y;
                p2 += wh[i + 1].z * hv1.z; p3 += wh[i + 1].w * hv1.w;
            }
            const float p = (p0 + p1) + (p2 + p3);
            if (m == 0) gA[j] = p + bsum;
            else        gB[j] = p;
        }
        __syncthreads();  // partials visible

        // ---- phase 2a: cell update on wave 7 ----
        if (u < len && w == 7) {
            const float gi = gA[l]       + gB[l];
            const float gf = gA[64 + l]  + gB[64 + l];
            const float gg = gA[128 + l] + gB[128 + l];
            const float go = gA[192 + l] + gB[192 + l];
            c = sigm(gf) * c + sigm(gi) * tanh_fast(gg);
            h_lds[u & 1][l] = sigm(go) * tanh_fast(c);
        }
        // ---- phase 2b: head for step u-1 (waves 0-1), reads h_{u-1} ----
        if (u >= 1 && t < KO4_) {
            const float4* hh = (const float4*)h_lds[(u + 1) & 1];
            float ph = dot4(wk[0], hh[q * 4 + 0]) + dot4(wk[1], hh[q * 4 + 1])
                     + dot4(wk[2], hh[q * 4 + 2]) + dot4(wk[3], hh[q * 4 + 3]);
            ph += __shfl_xor(ph, 1);
            ph += __shfl_xor(ph, 2);
            const float partner = __shfl_xor(hk, 4);
            if (q == 0) {
                const int o = gb & 1;
                const float h0 = (o == 0) ? hk : partner;
                const float h1 = (o == 0) ? partner : hk;
                hk = tanh_fast(ph + hbsum + whh0 * h0 + whh1 * h1);
                if (u == len) {
                    out[((gb >> 1) * B_ + b) * H2_ + o] = sigm(hk);
                }
            }
        }
        __syncthreads();  // h_u visible; gA/gB free for rewrite
        if (u == len) break;
    }
}

}  // namespace

extern "C" void kernel_launch(void* const* d_in, const int* in_sizes, int n_in,
                              void* d_out, int out_size, void* d_ws, size_t ws_size,
                              hipStream_t stream) {
    const float* x    = (const float*)d_in[0];
    const int*   len  = (const int*)d_in[1];
    const float* Wih  = (const float*)d_in[2];
    const float* Whh  = (const float*)d_in[3];
    const float* bih  = (const float*)d_in[4];
    const float* bhh  = (const float*)d_in[5];
    const float* hWih = (const float*)d_in[6];
    const float* hWhh = (const float*)d_in[7];
    const float* hbih = (const float*)d_in[8];
    const float* hbhh = (const float*)d_in[9];
    float* outp = (float*)d_out;

    hipLaunchKernelGGL(lstm_fused, dim3(B_), dim3(NTHR), 0, stream,
                       x, len, Wih, Whh, bih, bhh, hWih, hWhh, hbih, hbhh, outp);
}

// Round 4
// 2097.051 us; speedup vs baseline: 1.9846x; 1.9846x over previous
//
#include <hip/hip_runtime.h>
#include <cstddef>
#include <cstdint>

// LSTM_27934467293427 — R4: two-kernel decomposition.
// K1: gx = X·Wih^T + bias via split-bf16 MFMA (no recurrence -> fully parallel).
// K2: recurrence with only h·Whh^T per step (1/3 of old FLOPs), ONE barrier/step,
//     transpose-shuffle gate reduce, dedicated head wave, gx register prefetch.
// Chunked over S; state carried in d_ws between launches.

namespace {

constexpr int B_ = 256, S_ = 2048, E_ = 128, H_ = 64, G_ = 256, H2_ = 2;

typedef short short8 __attribute__((ext_vector_type(8)));
typedef float f4 __attribute__((ext_vector_type(4)));

__device__ __forceinline__ float sigm(float x) {
    return __builtin_amdgcn_rcpf(1.0f + __expf(-x));
}
__device__ __forceinline__ float tanh_fast(float x) {
    return 1.0f - 2.0f * __builtin_amdgcn_rcpf(1.0f + __expf(2.0f * x));
}
__device__ __forceinline__ float dot4(float4 a, float4 b) {
    return a.x * b.x + a.y * b.y + a.z * b.z + a.w * b.w;
}
__device__ __forceinline__ short f2bf(float f) {  // RNE float->bf16
    union { float f; uint32_t u; } a; a.f = f;
    uint32_t r = a.u + 0x7FFFu + ((a.u >> 16) & 1u);
    return (short)(r >> 16);
}
__device__ __forceinline__ float bf2f(short s) {
    union { uint32_t u; float f; } a; a.u = ((uint32_t)(uint16_t)s) << 16;
    return a.f;
}
__device__ __forceinline__ void cvt8(float4 a, float4 b, short8& hi, short8& lo) {
    float v[8] = {a.x, a.y, a.z, a.w, b.x, b.y, b.z, b.w};
    #pragma unroll
    for (int i = 0; i < 8; ++i) {
        short h = f2bf(v[i]);
        hi[i] = h;
        lo[i] = f2bf(v[i] - bf2f(h));
    }
}
#define PIN4(v) asm volatile("" : "+v"(v.x), "+v"(v.y), "+v"(v.z), "+v"(v.w))

// ---------------- K1: gx[b][tau][j] = sum_e x[b,cs+tau,e]*Wih[j,e] + bias[j] ----
// grid (B*Tc/128, 2), 256 thr. Wave w owns 32 cols; block owns 128 rows (8 slabs).
// MFMA 16x16x32 bf16, split precision: Ah*Bh + Al*Bh + Ah*Bl.
__global__ __launch_bounds__(256) void k1_gemm(
    const float* __restrict__ x, const int* __restrict__ lengths,
    const float* __restrict__ Wih, const float* __restrict__ bih,
    const float* __restrict__ bhh, float* __restrict__ gx, int cs, int tcLog)
{
    const int Tc = 1 << tcLog;
    const int t = threadIdx.x;
    const int lane = t & 63, wv = t >> 6;
    const int lm = lane & 15, quad = lane >> 4;
    const int nbase = blockIdx.y * 128 + wv * 32;
    const int rowblk = blockIdx.x * 128;

    // B-fragments (weights), held in registers for all 8 slabs.
    short8 Bh[2][4], Bl[2][4];
    float bias[2];
    #pragma unroll
    for (int nt = 0; nt < 2; ++nt) {
        const int n = nbase + nt * 16 + lm;
        bias[nt] = bih[n] + bhh[n];
        #pragma unroll
        for (int kk = 0; kk < 4; ++kk) {
            const float4* wp = (const float4*)(Wih + n * E_ + kk * 32 + quad * 8);
            cvt8(wp[0], wp[1], Bh[nt][kk], Bl[nt][kk]);
        }
    }

    for (int slab = 0; slab < 8; ++slab) {
        const int row0 = rowblk + slab * 16;
        const int b = row0 >> tcLog;
        const int tb = row0 & (Tc - 1);
        int len = lengths[b]; len = len < 1 ? 1 : (len > S_ ? S_ : len);
        if (cs + tb >= len) continue;

        // A-fragments: row m = lm, k = quad*8 + j (+32*kk)
        const float* xr = x + ((size_t)b * S_ + cs + tb + lm) * E_;
        short8 Ah[4], Al[4];
        #pragma unroll
        for (int kk = 0; kk < 4; ++kk) {
            const float4* ap = (const float4*)(xr + kk * 32 + quad * 8);
            cvt8(ap[0], ap[1], Ah[kk], Al[kk]);
        }
        f4 acc[2] = {{0,0,0,0},{0,0,0,0}};
        #pragma unroll
        for (int kk = 0; kk < 4; ++kk) {
            #pragma unroll
            for (int nt = 0; nt < 2; ++nt) {
                acc[nt] = __builtin_amdgcn_mfma_f32_16x16x32_bf16(Ah[kk], Bh[nt][kk], acc[nt], 0, 0, 0);
                acc[nt] = __builtin_amdgcn_mfma_f32_16x16x32_bf16(Al[kk], Bh[nt][kk], acc[nt], 0, 0, 0);
                acc[nt] = __builtin_amdgcn_mfma_f32_16x16x32_bf16(Ah[kk], Bl[nt][kk], acc[nt], 0, 0, 0);
            }
        }
        // D: col = lane&15, row = quad*4 + r (m89/m91-verified)
        float* gp = gx + ((size_t)b * Tc + tb) * G_;
        #pragma unroll
        for (int nt = 0; nt < 2; ++nt) {
            #pragma unroll
            for (int r = 0; r < 4; ++r) {
                gp[(quad * 4 + r) * G_ + nbase + nt * 16 + lm] = acc[nt][r] + bias[nt];
            }
        }
    }
}

// ---------------- K2: recurrence over one chunk [cs, cs+Tc) ---------------------
// 320 thr: t<256 gates (p=t>>2, q=t&3, gate j=q*64+p), wave 4 = head.
__global__ __launch_bounds__(320, 1) void k2_recur(
    const float* __restrict__ gx, const int* __restrict__ lengths,
    const float* __restrict__ Whh, const float* __restrict__ hWih,
    const float* __restrict__ hWhh, const float* __restrict__ hbih,
    const float* __restrict__ hbhh, float* __restrict__ out,
    float* __restrict__ stH, float* __restrict__ stC, float* __restrict__ stHK,
    int cs, int Tc)
{
    const int b = blockIdx.x, t = threadIdx.x;
    int len = lengths[b]; len = len < 1 ? 1 : (len > S_ ? S_ : len);
    if (cs > len) return;
    const int ce = cs + Tc;

    __shared__ __align__(16) float h_lds[2][H_];

    const bool isGate = t < 256;
    const int p = (t >> 2) & 63, q = t & 3;

    // Rotated gate weights: P_k accumulates gate (q^k) -> shuffle-transpose reduce.
    float4 wh[4][4];
    if (isGate) {
        #pragma unroll
        for (int k = 0; k < 4; ++k) {
            const int g = q ^ k;
            const float4* wp = (const float4*)(Whh + (g * 64 + p) * H_ + q * 16);
            #pragma unroll
            for (int i = 0; i < 4; ++i) wh[k][i] = wp[i];
        }
        #pragma unroll
        for (int k = 0; k < 4; ++k) {
            #pragma unroll
            for (int i = 0; i < 4; ++i) PIN4(wh[k][i]);
        }
    }

    // Head wave: th<52, ko=th>>1 (k=ko>>1, o=ko&1), half=th&1 covers 32 h-elems.
    const int th = t - 256;
    const bool isHead = (t >= 256) && (th < 52);
    const int ko = (th >> 1) & 31, half = th & 1;
    const int hk_k = ko >> 1, hk_o = ko & 1;
    float4 wk[8] = {};
    float hb = 0.f, w0 = 0.f, w1 = 0.f;
    if (isHead) {
        const int r = hk_k * 2 + hk_o;
        const float4* kp = (const float4*)(hWih + r * H_ + half * 32);
        #pragma unroll
        for (int i = 0; i < 8; ++i) wk[i] = kp[i];
        hb = hbih[r] + hbhh[r];
        w0 = hWhh[r * 2 + 0];
        w1 = hWhh[r * 2 + 1];
        #pragma unroll
        for (int i = 0; i < 8; ++i) PIN4(wk[i]);
    }

    float c = 0.f, hk = 0.f;
    if (cs == 0) {
        if (t < 64) h_lds[0][t] = 0.f;
    } else {
        if (t < 64) h_lds[cs & 1][t] = stH[b * 64 + t];
        if (isGate && q == 0) c = stC[b * 64 + p];
        if (isHead && half == 0) hk = stHK[b * 32 + ko];
    }
    __syncthreads();

    // gx prefetch pipeline (distance 2), thread t reads gx[.][q*64+p]
    const float* gxp = gx + (size_t)b * Tc * G_ + (q * 64 + p);
    float gxa = 0.f, gxb = 0.f;
    if (isGate) {
        if (cs < len) gxa = gxp[0];
        if (cs + 1 < len && cs + 1 < ce) gxb = gxp[G_];
    }

    auto headStep = [&](int u, const float* hbuf) {
        // computes hk_{u-1} from h_{u-1}; writes output when u == len
        const float4* hv = (const float4*)(hbuf + half * 32);
        float ph = 0.f;
        #pragma unroll
        for (int i = 0; i < 8; ++i) ph += dot4(wk[i], hv[i]);
        ph += __shfl_xor(ph, 1);
        const float partner = __shfl_xor(hk, 2);
        if (half == 0) {
            const float h0 = (hk_o == 0) ? hk : partner;
            const float h1 = (hk_o == 0) ? partner : hk;
            hk = tanh_fast(ph + hb + w0 * h0 + w1 * h1);
            if (u == len) out[(hk_k * B_ + b) * H2_ + hk_o] = sigm(hk);
        }
    };

    for (int u = cs; u < ce; ++u) {
        const float* hbuf = h_lds[u & 1];       // h_{u-1}
        if (u >= 1 && isHead) headStep(u, hbuf);
        if (u == len) return;                    // uniform: all threads exit

        if (isGate) {
            const float4* hv = (const float4*)(hbuf + q * 16);
            const float4 h0 = hv[0], h1 = hv[1], h2 = hv[2], h3 = hv[3];
            float P0 = dot4(wh[0][0], h0) + dot4(wh[0][1], h1) + dot4(wh[0][2], h2) + dot4(wh[0][3], h3);
            float P1 = dot4(wh[1][0], h0) + dot4(wh[1][1], h1) + dot4(wh[1][2], h2) + dot4(wh[1][3], h3);
            float P2 = dot4(wh[2][0], h0) + dot4(wh[2][1], h1) + dot4(wh[2][2], h2) + dot4(wh[2][3], h3);
            float P3 = dot4(wh[3][0], h0) + dot4(wh[3][1], h1) + dot4(wh[3][2], h2) + dot4(wh[3][3], h3);
            // transpose-reduce: lane q ends with full dot of gate q
            float a_  = P0 + __shfl_xor(P1, 1);
            float b2_ = P2 + __shfl_xor(P3, 1);
            float v   = a_ + __shfl_xor(b2_, 2) + gxa;
            // activation: q==2 -> tanh(v) = 2*sigm(2v)-1, else sigm(v)
            const bool isg = (q == 2);
            const float s = sigm(isg ? 2.f * v : v);
            const float act = isg ? 2.f * s - 1.f : s;
            const float r1 = __shfl_xor(act, 1);
            const float r2 = __shfl_xor(act, 2);
            const float r3 = __shfl_xor(act, 3);
            if (q == 0) {
                c = r1 * c + act * r2;                  // c = f*c + i*g
                h_lds[(u + 1) & 1][p] = r3 * tanh_fast(c);
            }
            gxa = gxb;
            const int un = u + 2;
            gxb = (un < len && un < ce) ? gxp[(size_t)(un - cs) * G_] : 0.f;
        }
        __syncthreads();
    }

    // chunk fully processed (len >= ce): persist state
    if (t < 64) stH[b * 64 + t] = h_lds[ce & 1][t];
    if (isGate && q == 0) stC[b * 64 + p] = c;
    if (isHead && half == 0) stHK[b * 32 + ko] = hk;

    if (ce == S_ && len == S_) {
        // lagged final head for h_{S-1}
        if (isHead) headStep(S_, h_lds[S_ & 1]);
    }
}

}  // namespace

extern "C" void kernel_launch(void* const* d_in, const int* in_sizes, int n_in,
                              void* d_out, int out_size, void* d_ws, size_t ws_size,
                              hipStream_t stream) {
    const float* x    = (const float*)d_in[0];
    const int*   len  = (const int*)d_in[1];
    const float* Wih  = (const float*)d_in[2];
    const float* Whh  = (const float*)d_in[3];
    const float* bih  = (const float*)d_in[4];
    const float* bhh  = (const float*)d_in[5];
    const float* hWih = (const float*)d_in[6];
    const float* hWhh = (const float*)d_in[7];
    const float* hbih = (const float*)d_in[8];
    const float* hbhh = (const float*)d_in[9];
    float* out = (float*)d_out;

    // pick chunk length fitting the workspace (gx chunk + 160KB state)
    int tcLog = 8;  // Tc = 256
    while (tcLog > 5) {
        size_t need = (size_t)B_ * ((size_t)1 << tcLog) * G_ * 4 + 160 * 1024;
        if (need <= ws_size) break;
        --tcLog;
    }
    const int Tc = 1 << tcLog;
    float* gxbuf = (float*)d_ws;
    size_t gxBytes = (size_t)B_ * Tc * G_ * 4;
    float* stH  = (float*)((char*)d_ws + gxBytes);
    float* stC  = stH + B_ * 64;
    float* stHK = stC + B_ * 64;

    for (int cs = 0; cs < S_; cs += Tc) {
        dim3 g1(B_ * Tc / 128, 2);
        hipLaunchKernelGGL(k1_gemm, g1, dim3(256), 0, stream,
                           x, len, Wih, bih, bhh, gxbuf, cs, tcLog);
        hipLaunchKernelGGL(k2_recur, dim3(B_), dim3(320), 0, stream,
                           gxbuf, len, Whh, hWih, hWhh, hbih, hbhh, out,
                           stH, stC, stHK, cs, Tc);
    }
}